// Round 2
// baseline (126.906 us; speedup 1.0000x reference)
//
#include <hip/hip_runtime.h>
#include <hip/hip_bf16.h>
#include <math.h>

// Problem constants
#define MM 12544   // 64 * 196 patches
#define KK 768     // 16*16*3
#define NN 768     // embedding dim
// GEMM tiling: BM=64, BN=256. A is im2col'd on the fly from the image
// (no apack round-trip); B comes pre-packed bf16 (wpack, 1.18 MB, L2-hot).
#define BM 64
#define BN 256
#define BK 64
#define KT 12              // KK/BK
#define MT 196             // MM/BM
#define NT 3               // NN/BN
#define TILE_B_BYTES (BN*BK*2)   // 32768

#define WTPACK_BLOCKS ((NN * 96) / 256)   // 288

typedef __bf16 v8bf __attribute__((ext_vector_type(8)));
typedef float  v4f  __attribute__((ext_vector_type(4)));

// ---------------------------------------------------------------------------
// Phase 1 (weights only): transpose+pack W to bf16.
// W-pack: [nt 0..2][kt 0..11][n 0..255][g^(n&7)][8] bf16
// xor swizzle keeps the GEMM's ds_read_b128 fragment reads conflict-free.
// ---------------------------------------------------------------------------
__global__ __launch_bounds__(256) void wpack_kernel(const float* __restrict__ w,
                                                    __hip_bfloat16* __restrict__ wpack) {
    int tid = blockIdx.x * 256 + threadIdx.x;  // 0 .. 768*96-1
    int n   = tid % 768;
    int gg  = tid / 768;
    int k0  = gg * 8;
    float f[8];
#pragma unroll
    for (int j = 0; j < 8; j++) f[j] = w[(size_t)(k0 + j) * NN + n];
    int nt = n >> 8;        // 256-col tiles
    int nr = n & 255;
    int kt = gg >> 3;
    int g  = gg & 7;
    int gs = g ^ (nr & 7);
    union { __hip_bfloat16 h[8]; uint4 u; } o;
#pragma unroll
    for (int j = 0; j < 8; j++) o.h[j] = __float2bfloat16(f[j]);
    *(uint4*)(wpack + ((size_t)(nt * KT + kt) * BN + nr) * BK + gs * 8) = o.u;
}

// Fast GELU: 0.5x(1+tanh(0.79788456(x+0.044715x^3))) = x * E/(E+1), E=e^{2t}.
// v_exp + v_rcp; max deviation from exact erf-GELU ~3e-3 << 0.103 threshold.
__device__ __forceinline__ float gelu_fast(float x) {
    float t2 = 1.5957691216057308f * x * (1.0f + 0.044715f * x * x);  // 2t
    float e  = __expf(t2);
    float r  = __builtin_amdgcn_rcpf(e + 1.0f);
    return x - x * r;   // x*(1 - 1/(E+1)) = x*E/(E+1)
}

// ---------------------------------------------------------------------------
// Phase 2: fused im2col + bf16 MFMA GEMM + bias + fast GELU.
// 64x256 block tile, 256 thr / 4 waves (wave = 64 rows x 64 cols, 1x4 in N).
// PIPELINED (T3-minimum 2-phase): double-buffered LDS (80 KB, 2 blocks/CU);
// per iteration: {issue B(t+1) global_load_lds + ds_write A(t+1) + prefetch
// A(t+2) regs} -> MFMA on buffers[t&1] -> ONE __syncthreads().  The forced
// vmcnt(0) at the barrier now sits AFTER the MFMA cluster, so every load has
// a full compute phase to land instead of being drained immediately.
// XCD chunked swizzle: the 3 nt-blocks of one mt share an XCD's L2.
// ---------------------------------------------------------------------------
__global__ __launch_bounds__(256, 2) void gemm_fused(const float* __restrict__ img,
                                                     const __hip_bfloat16* __restrict__ wpack,
                                                     const float* __restrict__ bias,
                                                     float* __restrict__ out) {
    __shared__ __align__(16) __hip_bfloat16 As[2][BM * BK];   // 2 x  8 KB
    __shared__ __align__(16) __hip_bfloat16 Bs[2][BN * BK];   // 2 x 32 KB

    // Bijective chunked XCD swizzle for NWG=588 (q=73, r=4): hardware id h
    // (round-robins XCDs as h%8) -> logical u contiguous per XCD.
    const int h   = blockIdx.x;
    const int xcd = h & 7;
    const int j   = h >> 3;
    const int u   = (xcd < 4 ? xcd * 74 : 296 + (xcd - 4) * 73) + j;
    const int nt  = u % 3;
    const int mt  = u / 3;

    const int tid  = threadIdx.x;
    const int lane = tid & 63;
    const int wave = tid >> 6;
    const int wn   = wave * 64;          // wave's N-offset within tile
    const int col  = lane & 15;
    const int quad = lane >> 4;
    const int cl7  = col & 7;

    // ---- im2col assignment: thread -> (patch row r within tile, chunk c) ----
    const int r  = tid >> 2;             // 0..63
    const int c  = tid & 3;              // 16-float chunk within 64-k slice
    const int m  = mt * BM + r;          // global patch index
    const int b  = m / 196;
    const int pm = m - b * 196;
    const int pr = pm / 14;
    const int pc = pm - pr * 14;
    const float* abase = img + (size_t)((b * 224 + pr * 16) * 224 + pc * 16) * 3;
    // k = kt*64 + c*16 + j ; i = k/48 (row in patch), rem = k%48.
    // Incremental: rem<32 -> i+=1, rem+=16 (ptr+688 floats);
    //              rem==32 -> i+=2, rem=0 (ptr+1312 floats).
    int rem = (c == 3) ? 0 : c * 16;
    const float* asrc = abase + ((c == 3) ? 672 : 0) + rem;
    // Swizzled LDS slots for this thread's two k-groups (g = 2c, 2c+1)
    const int s0   = (2 * c) ^ (r & 7);
    const int aoff0 = r * BK + s0 * 8;
    const int aoff1 = r * BK + (s0 ^ 1) * 8;

    v4f acc[4][4];
    const v4f vzero = {0.f, 0.f, 0.f, 0.f};
#pragma unroll
    for (int a = 0; a < 4; a++)
#pragma unroll
        for (int cc = 0; cc < 4; cc++) acc[a][cc] = vzero;

    const char* bT = (const char*)wpack + (size_t)nt * KT * TILE_B_BYTES;

#define LOAD_A_REGS()                                            \
    {   const float4* ap = (const float4*)asrc;                  \
        a0 = ap[0]; a1 = ap[1]; a2 = ap[2]; a3 = ap[3];          \
        asrc += (rem < 32) ? 688 : 1312;                         \
        rem   = (rem < 32) ? rem + 16 : 0;  }

#define STAGE_B(buf)                                                          \
    {   _Pragma("unroll")                                                     \
        for (int p = 0; p < 8; p++) {                                         \
            int off = p * 4096 + tid * 16;                                    \
            __builtin_amdgcn_global_load_lds(                                 \
                (const __attribute__((address_space(1))) void*)(bT + off),    \
                (__attribute__((address_space(3))) void*)((char*)Bs[buf] + off), \
                16, 0, 0);                                                    \
        }                                                                     \
        bT += TILE_B_BYTES;  }

#define WRITE_A(buf)                                                          \
    {   union { __hip_bfloat16 hh[8]; uint4 uu; } o0, o1;                     \
        o0.hh[0] = __float2bfloat16(a0.x); o0.hh[1] = __float2bfloat16(a0.y); \
        o0.hh[2] = __float2bfloat16(a0.z); o0.hh[3] = __float2bfloat16(a0.w); \
        o0.hh[4] = __float2bfloat16(a1.x); o0.hh[5] = __float2bfloat16(a1.y); \
        o0.hh[6] = __float2bfloat16(a1.z); o0.hh[7] = __float2bfloat16(a1.w); \
        o1.hh[0] = __float2bfloat16(a2.x); o1.hh[1] = __float2bfloat16(a2.y); \
        o1.hh[2] = __float2bfloat16(a2.z); o1.hh[3] = __float2bfloat16(a2.w); \
        o1.hh[4] = __float2bfloat16(a3.x); o1.hh[5] = __float2bfloat16(a3.y); \
        o1.hh[6] = __float2bfloat16(a3.z); o1.hh[7] = __float2bfloat16(a3.w); \
        *(uint4*)(As[buf] + aoff0) = o0.uu;                                   \
        *(uint4*)(As[buf] + aoff1) = o1.uu;  }

#define COMPUTE(buf)                                                          \
    {   _Pragma("unroll")                                                     \
        for (int ks = 0; ks < 2; ks++) {                                      \
            const int gs = (ks * 4 + quad) ^ cl7;                             \
            const v8bf* pa = (const v8bf*)(As[buf] + col * BK + gs * 8);      \
            const v8bf* pb = (const v8bf*)(Bs[buf] + (wn + col) * BK + gs * 8);\
            v8bf af[4], bfr[4];                                               \
            _Pragma("unroll")                                                 \
            for (int mi = 0; mi < 4; mi++) af[mi] = pa[mi * 128];             \
            _Pragma("unroll")                                                 \
            for (int ni = 0; ni < 4; ni++) bfr[ni] = pb[ni * 128];            \
            _Pragma("unroll")                                                 \
            for (int mi = 0; mi < 4; mi++)                                    \
                _Pragma("unroll")                                             \
                for (int ni = 0; ni < 4; ni++)                                \
                    acc[mi][ni] = __builtin_amdgcn_mfma_f32_16x16x32_bf16(    \
                        af[mi], bfr[ni], acc[mi][ni], 0, 0, 0);               \
        }  }

    // ---- prologue: fill buffer 0, prefetch A(1) regs ----
    float4 a0, a1, a2, a3;
    LOAD_A_REGS();            // A(0)
    STAGE_B(0);               // B(0) -> Bs[0]
    WRITE_A(0);               // waits A(0) regs, writes As[0]
    LOAD_A_REGS();            // A(1)
    __syncthreads();          // drains B(0) + A(1) reg loads

    // ---- main loop: issue-early, drain-late, one barrier per iteration ----
#pragma unroll
    for (int t = 0; t < KT - 1; t++) {
        const int cur = t & 1;
        STAGE_B(cur ^ 1);                 // B(t+1), in flight across compute
        WRITE_A(cur ^ 1);                 // A(t+1) from regs (ready)
        if (t < KT - 2) LOAD_A_REGS();    // A(t+2), lands during compute
        COMPUTE(cur);
        __syncthreads();                  // vmcnt(0)+lgkmcnt(0) AFTER compute
    }
    COMPUTE((KT - 1) & 1);                // t = 11, buffers[1]

    // ---- epilogue: bias + fast GELU, coalesced fp32 stores ----
#pragma unroll
    for (int ni = 0; ni < 4; ni++) {
        int n    = nt * BN + wn + ni * 16 + col;
        float bv = bias[n];
#pragma unroll
        for (int mi = 0; mi < 4; mi++) {
            int rowb = mt * BM + mi * 16 + quad * 4;
            float* po = out + (size_t)rowb * NN + n;
#pragma unroll
            for (int rg = 0; rg < 4; rg++) {
                float x = acc[mi][ni][rg] + bv;
                po[(size_t)rg * NN] = gelu_fast(x);
            }
        }
    }
#undef LOAD_A_REGS
#undef STAGE_B
#undef WRITE_A
#undef COMPUTE
}

extern "C" void kernel_launch(void* const* d_in, const int* in_sizes, int n_in,
                              void* d_out, int out_size, void* d_ws, size_t ws_size,
                              hipStream_t stream) {
    const float* img   = (const float*)d_in[0];   // [64,224,224,3]
    const float* wproj = (const float*)d_in[1];   // [768,768]
    const float* bias  = (const float*)d_in[2];   // [768]
    float* out = (float*)d_out;                   // [64,196,768]

    __hip_bfloat16* wpack = (__hip_bfloat16*)d_ws;   // 1,179,648 B

    wpack_kernel<<<dim3(WTPACK_BLOCKS), dim3(256), 0, stream>>>(wproj, wpack);
    gemm_fused<<<dim3(MT * NT), dim3(256), 0, stream>>>(img, wpack, bias, out);
}

// Round 3
// 119.764 us; speedup vs baseline: 1.0596x; 1.0596x over previous
//
#include <hip/hip_runtime.h>
#include <hip/hip_bf16.h>
#include <math.h>

// Problem constants
#define MM 12544   // 64 * 196 patches
#define KK 768     // 16*16*3
#define NN 768     // embedding dim
// LDS-free GEMM: BM=64, BN=256, 4 waves 1x4 in N (each wave 64x64 output).
// A and B are pre-packed into FRAGMENT-LANE-MAJOR layout: one MFMA fragment
// (16 rows/cols x 32 k, 64 lanes x 16B) = one contiguous 1KB chunk.
// The GEMM loads fragments global->register directly: no LDS, no barriers,
// no forced vmcnt(0) drains -- loads pipeline freely across the K-loop.
#define BM 64
#define BN 256
#define NKS 24             // KK / 32 k-steps
#define MT 196             // MM/BM
#define NT 3               // NN/BN
#define N64 12             // NN/64 wave-column groups

#define A_BLOCKS (MT * NKS)    // 4704
#define W_BLOCKS (N64 * NKS)   // 288
#define FRAG_BYTES 1024        // 64 lanes x 16B
#define KSTRIDE (4 * FRAG_BYTES)          // per-ks: 4 frags = 4KB
#define PANEL_BYTES (NKS * KSTRIDE)       // 96KB per 64-row/col panel

typedef __bf16 v8bf __attribute__((ext_vector_type(8)));
typedef float  v4f  __attribute__((ext_vector_type(4)));

// ---------------------------------------------------------------------------
// Pack: im2col A and transpose W into fragment-lane-major bf16 chunks.
// A chunk id: ((mt*24 + ks)*4 + mi)*64 + lane ; lane l = (k8=l>>4, row=l&15)
//   holds A[mt*64 + mi*16 + (l&15)][ks*32 + (l>>4)*8 .. +8]
// W chunk id: ((n64*24 + ks)*4 + ni)*64 + lane
//   holds W[ks*32 + (l>>4)*8 .. +8][n64*64 + ni*16 + (l&15)]
// Writes are perfectly coalesced (chunk addr = base + tid*16).
// ---------------------------------------------------------------------------
__global__ __launch_bounds__(256) void pack_kernel(const float* __restrict__ img,
                                                   const float* __restrict__ w,
                                                   __hip_bfloat16* __restrict__ apack,
                                                   __hip_bfloat16* __restrict__ wpack) {
    const int tid  = threadIdx.x;
    const int l    = tid & 63;
    const int fi   = tid >> 6;      // mi or ni (0..3)
    const int l_lo = l & 15;        // row / col within fragment
    const int l_hi = l >> 4;        // 8-k group within 32

    union { __hip_bfloat16 h[8]; uint4 u; } o;

    if (blockIdx.x < A_BLOCKS) {
        const int bid = blockIdx.x;
        const int mt  = bid / NKS;
        const int ks  = bid - mt * NKS;
        const int m   = mt * 64 + fi * 16 + l_lo;   // global patch index
        const int k0  = ks * 32 + l_hi * 8;         // k within 768
        const int b   = m / 196;
        const int pm  = m - b * 196;
        const int pr  = pm / 14;
        const int pc  = pm - pr * 14;
        const int i   = k0 / 48;                    // row within patch
        const int rem = k0 - i * 48;                // 8-aligned, <=40
        const float* src = img + (size_t)(((b * 224 + pr * 16 + i) * 224 + pc * 16) * 3 + rem);
        float4 f0 = *(const float4*)src;            // 16B-aligned (rem mult of 8 floats)
        float4 f1 = *(const float4*)(src + 4);
        o.h[0] = __float2bfloat16(f0.x); o.h[1] = __float2bfloat16(f0.y);
        o.h[2] = __float2bfloat16(f0.z); o.h[3] = __float2bfloat16(f0.w);
        o.h[4] = __float2bfloat16(f1.x); o.h[5] = __float2bfloat16(f1.y);
        o.h[6] = __float2bfloat16(f1.z); o.h[7] = __float2bfloat16(f1.w);
        ((uint4*)apack)[(size_t)((mt * NKS + ks) * 4 + fi) * 64 + l] = o.u;
    } else {
        const int bid = blockIdx.x - A_BLOCKS;
        const int n64 = bid / NKS;
        const int ks  = bid - n64 * NKS;
        const int col = n64 * 64 + fi * 16 + l_lo;
        const int k0  = ks * 32 + l_hi * 8;
        float f[8];
#pragma unroll
        for (int j = 0; j < 8; j++) f[j] = w[(size_t)(k0 + j) * NN + col];
#pragma unroll
        for (int j = 0; j < 8; j++) o.h[j] = __float2bfloat16(f[j]);
        ((uint4*)wpack)[(size_t)((n64 * NKS + ks) * 4 + fi) * 64 + l] = o.u;
    }
}

// Fast GELU: 0.5x(1+tanh(0.79788456(x+0.044715x^3))) = x * E/(E+1), E=e^{2t}.
// v_exp + v_rcp; max deviation from exact erf-GELU ~3e-3 << 0.103 threshold.
__device__ __forceinline__ float gelu_fast(float x) {
    float t2 = 1.5957691216057308f * x * (1.0f + 0.044715f * x * x);  // 2t
    float e  = __expf(t2);
    float r  = __builtin_amdgcn_rcpf(e + 1.0f);
    return x - x * r;   // x*(1 - 1/(E+1)) = x*E/(E+1)
}

// ---------------------------------------------------------------------------
// LDS-free MFMA GEMM + bias + fast GELU.
// 64x256 tile, 4 waves 1x4 in N. Fragments load straight to VGPRs from the
// packed buffers (A-frags 4x-duplicated across waves -> L1 hits; B-frags
// wave-private). Register double-buffer, 1 k-step lookahead; NO barriers,
// so the compiler's counted vmcnt keeps 8 loads in flight per wave and
// nothing ever drains to vmcnt(0) inside the loop.
// XCD chunked swizzle (bijective for 588): 3 nt-blocks of one mt share L2.
// ---------------------------------------------------------------------------
__global__ __launch_bounds__(256, 3) void gemm_reg(const __hip_bfloat16* __restrict__ apack,
                                                   const __hip_bfloat16* __restrict__ wpack,
                                                   const float* __restrict__ bias,
                                                   float* __restrict__ out) {
    const int h   = blockIdx.x;
    const int xcd = h & 7;
    const int jj  = h >> 3;
    const int u   = (xcd < 4 ? xcd * 74 : 296 + (xcd - 4) * 73) + jj;
    const int nt  = u % 3;
    const int mt  = u / 3;

    const int tid  = threadIdx.x;
    const int lane = tid & 63;
    const int wave = tid >> 6;
    const int col  = lane & 15;
    const int quad = lane >> 4;

    const char* pA = (const char*)apack + (size_t)mt * PANEL_BYTES + lane * 16;
    const char* pB = (const char*)wpack + (size_t)(nt * 4 + wave) * PANEL_BYTES + lane * 16;

    v4f acc[4][4];
    const v4f vzero = {0.f, 0.f, 0.f, 0.f};
#pragma unroll
    for (int a = 0; a < 4; a++)
#pragma unroll
        for (int c = 0; c < 4; c++) acc[a][c] = vzero;

    v8bf aR[2][4], bR[2][4];
    // preload ks = 0
#pragma unroll
    for (int mi = 0; mi < 4; mi++) aR[0][mi] = *(const v8bf*)(pA + mi * FRAG_BYTES);
#pragma unroll
    for (int ni = 0; ni < 4; ni++) bR[0][ni] = *(const v8bf*)(pB + ni * FRAG_BYTES);

#pragma unroll
    for (int ks = 0; ks < NKS; ks++) {
        const int cur = ks & 1;          // literal after full unroll
        if (ks + 1 < NKS) {
            const char* qA = pA + (size_t)(ks + 1) * KSTRIDE;
            const char* qB = pB + (size_t)(ks + 1) * KSTRIDE;
#pragma unroll
            for (int mi = 0; mi < 4; mi++)
                aR[cur ^ 1][mi] = *(const v8bf*)(qA + mi * FRAG_BYTES);
#pragma unroll
            for (int ni = 0; ni < 4; ni++)
                bR[cur ^ 1][ni] = *(const v8bf*)(qB + ni * FRAG_BYTES);
        }
#pragma unroll
        for (int mi = 0; mi < 4; mi++)
#pragma unroll
            for (int ni = 0; ni < 4; ni++)
                acc[mi][ni] = __builtin_amdgcn_mfma_f32_16x16x32_bf16(
                    aR[cur][mi], bR[cur][ni], acc[mi][ni], 0, 0, 0);
    }

    // ---- epilogue: bias + fast GELU, coalesced fp32 stores ----
#pragma unroll
    for (int ni = 0; ni < 4; ni++) {
        int n    = nt * BN + wave * 64 + ni * 16 + col;
        float bv = bias[n];
#pragma unroll
        for (int mi = 0; mi < 4; mi++) {
            int rowb = mt * BM + mi * 16 + quad * 4;
            float* po = out + (size_t)rowb * NN + n;
#pragma unroll
            for (int rg = 0; rg < 4; rg++) {
                float x = acc[mi][ni][rg] + bv;
                po[(size_t)rg * NN] = gelu_fast(x);
            }
        }
    }
}

extern "C" void kernel_launch(void* const* d_in, const int* in_sizes, int n_in,
                              void* d_out, int out_size, void* d_ws, size_t ws_size,
                              hipStream_t stream) {
    const float* img   = (const float*)d_in[0];   // [64,224,224,3]
    const float* wproj = (const float*)d_in[1];   // [768,768]
    const float* bias  = (const float*)d_in[2];   // [768]
    float* out = (float*)d_out;                   // [64,196,768]

    __hip_bfloat16* apack = (__hip_bfloat16*)d_ws;                        // 19,267,584 B
    __hip_bfloat16* wpack = (__hip_bfloat16*)((char*)d_ws + (size_t)MM * KK * 2);
    // total ws need: 20,447,232 B

    pack_kernel<<<dim3(A_BLOCKS + W_BLOCKS), dim3(256), 0, stream>>>(
        img, wproj, apack, wpack);
    gemm_reg<<<dim3(MT * NT), dim3(256), 0, stream>>>(apack, wpack, bias, out);
}